// Round 7
// baseline (129.909 us; speedup 1.0000x reference)
//
#include <hip/hip_runtime.h>

#define C_DIM 2048
#define T_TOKENS 4096

typedef float v4f __attribute__((ext_vector_type(4)));

// Fused scores + per-batch top-k via last-block election.
// Cross-XCD visibility is per-access (agent-scope atomics, sc1 write-through)
// -- NO __threadfence(): round 4 showed per-block device fences cost ~10x
// (L2 writeback/invalidate storm). Relaxed orderings keep the codegen to
// plain coherent loads/stores with zero cache-maintenance instructions.
__global__ __launch_bounds__(256) void fused_kernel(
    const float* __restrict__ hidden, const float* __restrict__ keep_ratio,
    const float* __restrict__ W, const float* __restrict__ bptr,
    float* __restrict__ mask_out, float* __restrict__ scores_out,
    int* __restrict__ counters, int blocks_per_batch) {
  const int tid = threadIdx.x;
  const int lane = tid & 63;
  const int wv = tid >> 6;
  const int token = blockIdx.x * 4 + wv;
  const int b = token >> 12;  // 4096 tokens per batch

  // ---- Phase 1: score[token] = dot(hidden[token,:], W) + b0 ----
  // Round-6-validated numerics: 4 independent f64 chains, exact products;
  // summation-order perturbation ~1e-16 << any f32 key gap.
  {
    const float* row = hidden + (size_t)token * C_DIM;
    double ax = 0.0, ay = 0.0, az = 0.0, aw = 0.0;
#pragma unroll
    for (int it = 0; it < C_DIM / 256; ++it) {
      const int c = it * 256 + lane * 4;
      v4f h = *reinterpret_cast<const v4f*>(row + c);
      v4f w = *reinterpret_cast<const v4f*>(W + c);
      ax += (double)h.x * (double)w.x;
      ay += (double)h.y * (double)w.y;
      az += (double)h.z * (double)w.z;
      aw += (double)h.w * (double)w.w;
    }
    double acc = (ax + ay) + (az + aw);
    for (int o = 32; o; o >>= 1) acc += __shfl_xor(acc, o);
    if (lane == 0) {
      float sv = (float)(acc + (double)bptr[0]);
      // agent-scope store: write-through past the non-coherent per-XCD L2.
      __hip_atomic_store(scores_out + token, sv, __ATOMIC_RELAXED,
                         __HIP_MEMORY_SCOPE_AGENT);
    }
  }

  // ---- Election: last-arriving block of batch b runs the top-k ----
  __shared__ int s_elect;
  __syncthreads();  // compiler drains vmcnt(0) here: score stores retired
  if (tid == 0) {
    int old = __hip_atomic_fetch_add(counters + b, 1, __ATOMIC_RELAXED,
                                     __HIP_MEMORY_SCOPE_AGENT);
    s_elect = (old == blocks_per_batch - 1) ? 1 : 0;
  }
  __syncthreads();
  if (!s_elect) return;

  // ---- Phase 2: variable-k top-k mask for batch b (round-2 radix) ----
  const float* scores = scores_out + (size_t)b * T_TOKENS;
  __shared__ int s_hist[256];
  __shared__ int s_wave[4];
  __shared__ unsigned int s_sel;
  __shared__ int s_krem;

  // k = max(1, trunc(clip(kr, 0.1, 1.0) * T)); *4096 is a pure exponent
  // shift in fp32 -> exact, truncation matches jnp int32 cast bit-for-bit.
  float kf = fminf(fmaxf(keep_ratio[b], 0.1f), 1.0f);
  int k = (int)(kf * (float)T_TOKENS);
  if (k < 1) k = 1;

  // Thread tid owns tokens [tid*16, tid*16+16). Agent-scope loads bypass
  // this XCD's (possibly stale) L1/L2 and read the coherent point.
  unsigned int key[16];
  const float* base = scores + tid * 16;
#pragma unroll
  for (int i = 0; i < 16; ++i) {
    float s = __hip_atomic_load(base + i, __ATOMIC_RELAXED,
                                __HIP_MEMORY_SCOPE_AGENT);
    unsigned int u = __float_as_uint(s);
    key[i] = (u & 0x80000000u) ? ~u : (u | 0x80000000u);
  }

  // 4-round byte radix descent: after round r, prefix = top (r+1) bytes of
  // the k-th largest key; krem = remaining quota within that prefix.
  unsigned int prefix = 0u;
  int krem = k;
#pragma unroll
  for (int round = 0; round < 4; ++round) {
    const int shift = 24 - 8 * round;
    const unsigned int pmask = (round == 0) ? 0u : (0xFFFFFFFFu << (shift + 8));

    s_hist[tid] = 0;
    __syncthreads();
#pragma unroll
    for (int i = 0; i < 16; ++i) {
      if ((key[i] & pmask) == prefix)
        atomicAdd(&s_hist[(key[i] >> shift) & 255], 1);
    }
    __syncthreads();

    // Inclusive suffix sum over 256 bins (bin index == tid).
    int v = s_hist[tid];
    int x = v;
#pragma unroll
    for (int off = 1; off < 64; off <<= 1) {
      int y = __shfl_down(x, off);
      if (lane + off < 64) x += y;
    }
    if (lane == 0) s_wave[wv] = x;
    __syncthreads();
    int add = 0;
    for (int w = wv + 1; w < 4; ++w) add += s_wave[w];
    const int suffix_incl = x + add;         // active keys in bins >= tid
    const int suffix_excl = suffix_incl - v; // bins > tid
    if (suffix_excl < krem && suffix_incl >= krem) {  // unique crossing bin
      s_sel = (unsigned int)tid;
      s_krem = krem - suffix_excl;
    }
    __syncthreads();
    prefix |= (s_sel << shift);
    krem = s_krem;
    __syncthreads();
  }
  // prefix = key of k-th largest; krem = # ties (by index order) to keep.

  // Stable tie-break: exclusive count of equal keys at smaller token index.
  int cnt = 0;
#pragma unroll
  for (int i = 0; i < 16; ++i) cnt += (key[i] == prefix) ? 1 : 0;
  int inc = cnt;
#pragma unroll
  for (int off = 1; off < 64; off <<= 1) {
    int y = __shfl_up(inc, off);
    if (lane >= off) inc += y;
  }
  if (lane == 63) s_wave[wv] = inc;
  __syncthreads();
  int waveoff = 0;
  for (int w = 0; w < wv; ++w) waveoff += s_wave[w];
  int run = waveoff + inc - cnt;  // equal keys strictly before my first token

  float* mrow = mask_out + (size_t)b * T_TOKENS + tid * 16;
#pragma unroll
  for (int i = 0; i < 16; i += 4) {
    float4 m4;
    float mv[4];
#pragma unroll
    for (int j = 0; j < 4; ++j) {
      unsigned int kk = key[i + j];
      bool keep = (kk > prefix) || (kk == prefix && run < krem);
      run += (kk == prefix) ? 1 : 0;
      mv[j] = keep ? 1.0f : 0.0f;
    }
    m4.x = mv[0]; m4.y = mv[1]; m4.z = mv[2]; m4.w = mv[3];
    *reinterpret_cast<float4*>(mrow + i) = m4;
  }
}

extern "C" void kernel_launch(void* const* d_in, const int* in_sizes, int n_in,
                              void* d_out, int out_size, void* d_ws, size_t ws_size,
                              hipStream_t stream) {
  const float* hidden = (const float*)d_in[0];
  const float* keep_ratio = (const float*)d_in[1];
  const float* W = (const float*)d_in[2];
  const float* bptr = (const float*)d_in[3];

  const int B = in_sizes[1];
  const int n_tokens = in_sizes[0] / C_DIM;  // B*T = 32768

  float* out = (float*)d_out;
  float* mask = out;                       // output 0: [B, T] mask as 0/1 float
  float* scores = out + (size_t)n_tokens;  // output 1: [B, T] fp32 scores

  int* counters = (int*)d_ws;
  (void)hipMemsetAsync(counters, 0, (size_t)B * sizeof(int), stream);

  const int blocks = n_tokens / 4;  // 4 waves/block, 1 token/wave
  fused_kernel<<<blocks, 256, 0, stream>>>(hidden, keep_ratio, W, bptr, mask,
                                           scores, counters, blocks / B);
}

// Round 8
// 49.099 us; speedup vs baseline: 2.6459x; 2.6459x over previous
//
#include <hip/hip_runtime.h>

#define C_DIM 2048
#define T_TOKENS 4096

typedef float v4f __attribute__((ext_vector_type(4)));

// Kernel 1: scores[n] = dot(hidden[n, :], W) + b0, one wave per token
// (round-2/6 structure, validated). Round-8 change: nontemporal loads on
// hidden (single-use stream -> skip cache allocate). Numerics unchanged:
// exact f64 products, 4 independent chains (validated r6).
__global__ __launch_bounds__(256) void score_kernel(
    const float* __restrict__ hidden, const float* __restrict__ W,
    const float* __restrict__ bptr, float* __restrict__ scores, int n_tokens) {
  const int wave = (int)((blockIdx.x * blockDim.x + threadIdx.x) >> 6);
  const int lane = threadIdx.x & 63;
  if (wave >= n_tokens) return;
  const float* row = hidden + (size_t)wave * C_DIM;
  double ax = 0.0, ay = 0.0, az = 0.0, aw = 0.0;
#pragma unroll
  for (int it = 0; it < C_DIM / (64 * 4); ++it) {
    const int c = it * 256 + lane * 4;
    v4f h = __builtin_nontemporal_load(reinterpret_cast<const v4f*>(row + c));
    v4f w = *reinterpret_cast<const v4f*>(W + c);
    ax += (double)h.x * (double)w.x;
    ay += (double)h.y * (double)w.y;
    az += (double)h.z * (double)w.z;
    aw += (double)h.w * (double)w.w;
  }
  double acc = (ax + ay) + (az + aw);
  for (int o = 32; o; o >>= 1) acc += __shfl_xor(acc, o);
  if (lane == 0) scores[wave] = (float)(acc + (double)bptr[0]);
}

// Kernel 2: per-batch variable-k top-k mask via 8-bit radix histogram descent
// (validated round 2, unchanged). Thread tid owns tokens [tid*16, tid*16+16);
// stable tie-break (smaller index first) matches argsort(argsort) rank.
__global__ __launch_bounds__(256) void topk_mask_kernel(
    const float* __restrict__ keep_ratio, const float* __restrict__ scores_all,
    float* __restrict__ mask) {
  const int b = blockIdx.x;
  const float* scores = scores_all + (size_t)b * T_TOKENS;
  __shared__ int s_hist[256];
  __shared__ int s_wave[4];
  __shared__ unsigned int s_sel;
  __shared__ int s_krem;
  const int tid = threadIdx.x;
  const int lane = tid & 63;
  const int wv = tid >> 6;

  // k = max(1, trunc(clip(kr, 0.1, 1.0) * T)); *4096 is a pure exponent
  // shift in fp32 -> exact, truncation matches jnp int32 cast bit-for-bit.
  float kf = fminf(fmaxf(keep_ratio[b], 0.1f), 1.0f);
  int k = (int)(kf * (float)T_TOKENS);
  if (k < 1) k = 1;

  // Load 16 contiguous scores -> order-preserving uint keys.
  unsigned int key[16];
  const float* base = scores + tid * 16;
#pragma unroll
  for (int i = 0; i < 16; i += 4) {
    float4 s4 = *reinterpret_cast<const float4*>(base + i);
    float ss[4] = {s4.x, s4.y, s4.z, s4.w};
#pragma unroll
    for (int j = 0; j < 4; ++j) {
      unsigned int u = __float_as_uint(ss[j]);
      key[i + j] = (u & 0x80000000u) ? ~u : (u | 0x80000000u);
    }
  }

  // 4-round byte radix descent: after round r, prefix = top (r+1) bytes of
  // the k-th largest key; krem = remaining quota within that prefix.
  unsigned int prefix = 0u;
  int krem = k;
#pragma unroll
  for (int round = 0; round < 4; ++round) {
    const int shift = 24 - 8 * round;
    const unsigned int pmask = (round == 0) ? 0u : (0xFFFFFFFFu << (shift + 8));

    s_hist[tid] = 0;
    __syncthreads();
#pragma unroll
    for (int i = 0; i < 16; ++i) {
      if ((key[i] & pmask) == prefix)
        atomicAdd(&s_hist[(key[i] >> shift) & 255], 1);
    }
    __syncthreads();

    // Inclusive suffix sum over 256 bins (bin index == tid).
    int v = s_hist[tid];
    int x = v;
#pragma unroll
    for (int off = 1; off < 64; off <<= 1) {
      int y = __shfl_down(x, off);
      if (lane + off < 64) x += y;
    }
    if (lane == 0) s_wave[wv] = x;
    __syncthreads();
    int add = 0;
    for (int w = wv + 1; w < 4; ++w) add += s_wave[w];
    const int suffix_incl = x + add;         // active keys in bins >= tid
    const int suffix_excl = suffix_incl - v; // bins > tid
    if (suffix_excl < krem && suffix_incl >= krem) {  // unique crossing bin
      s_sel = (unsigned int)tid;
      s_krem = krem - suffix_excl;
    }
    __syncthreads();
    prefix |= (s_sel << shift);
    krem = s_krem;
    __syncthreads();
  }
  // prefix = key of k-th largest; krem = # ties (by index order) to keep.

  // Stable tie-break: exclusive count of equal keys at smaller token index.
  int cnt = 0;
#pragma unroll
  for (int i = 0; i < 16; ++i) cnt += (key[i] == prefix) ? 1 : 0;
  int inc = cnt;
#pragma unroll
  for (int off = 1; off < 64; off <<= 1) {
    int y = __shfl_up(inc, off);
    if (lane >= off) inc += y;
  }
  if (lane == 63) s_wave[wv] = inc;
  __syncthreads();
  int waveoff = 0;
  for (int w = 0; w < wv; ++w) waveoff += s_wave[w];
  int run = waveoff + inc - cnt;  // equal keys strictly before my first token

  float* mrow = mask + (size_t)b * T_TOKENS + tid * 16;
#pragma unroll
  for (int i = 0; i < 16; i += 4) {
    float4 m4;
    float mv[4];
#pragma unroll
    for (int j = 0; j < 4; ++j) {
      unsigned int kk = key[i + j];
      bool keep = (kk > prefix) || (kk == prefix && run < krem);
      run += (kk == prefix) ? 1 : 0;
      mv[j] = keep ? 1.0f : 0.0f;
    }
    m4.x = mv[0]; m4.y = mv[1]; m4.z = mv[2]; m4.w = mv[3];
    *reinterpret_cast<float4*>(mrow + i) = m4;
  }
}

extern "C" void kernel_launch(void* const* d_in, const int* in_sizes, int n_in,
                              void* d_out, int out_size, void* d_ws, size_t ws_size,
                              hipStream_t stream) {
  const float* hidden = (const float*)d_in[0];
  const float* keep_ratio = (const float*)d_in[1];
  const float* W = (const float*)d_in[2];
  const float* bptr = (const float*)d_in[3];

  const int B = in_sizes[1];
  const int n_tokens = in_sizes[0] / C_DIM;  // B*T = 32768

  float* out = (float*)d_out;
  float* mask = out;                       // output 0: [B, T] mask as 0/1 float
  float* scores = out + (size_t)n_tokens;  // output 1: [B, T] fp32 scores

  // 4 waves/block, 1 token/wave (round-2 structure).
  const int blocks = (n_tokens + 3) / 4;
  score_kernel<<<blocks, 256, 0, stream>>>(hidden, W, bptr, scores, n_tokens);
  topk_mask_kernel<<<B, 256, 0, stream>>>(keep_ratio, scores, mask);
}

// Round 9
// 48.125 us; speedup vs baseline: 2.6994x; 1.0202x over previous
//
#include <hip/hip_runtime.h>

#define C_DIM 2048
#define T_TOKENS 4096

typedef float v4f __attribute__((ext_vector_type(4)));

// Kernel 1: scores[n] = dot(hidden[n, :], W) + b0, one wave per token
// (validated r2/r6/r8). nt loads on hidden (single-use stream). Numerics:
// exact f64 products, 4 independent chains -- DO NOT PERTURB.
__global__ __launch_bounds__(256) void score_kernel(
    const float* __restrict__ hidden, const float* __restrict__ W,
    const float* __restrict__ bptr, float* __restrict__ scores, int n_tokens) {
  const int wave = (int)((blockIdx.x * blockDim.x + threadIdx.x) >> 6);
  const int lane = threadIdx.x & 63;
  if (wave >= n_tokens) return;
  const float* row = hidden + (size_t)wave * C_DIM;
  double ax = 0.0, ay = 0.0, az = 0.0, aw = 0.0;
#pragma unroll
  for (int it = 0; it < C_DIM / (64 * 4); ++it) {
    const int c = it * 256 + lane * 4;
    v4f h = __builtin_nontemporal_load(reinterpret_cast<const v4f*>(row + c));
    v4f w = *reinterpret_cast<const v4f*>(W + c);
    ax += (double)h.x * (double)w.x;
    ay += (double)h.y * (double)w.y;
    az += (double)h.z * (double)w.z;
    aw += (double)h.w * (double)w.w;
  }
  double acc = (ax + ay) + (az + aw);
  for (int o = 32; o; o >>= 1) acc += __shfl_xor(acc, o);
  if (lane == 0) scores[wave] = (float)(acc + (double)bptr[0]);
}

// Kernel 2 (round-9 rewrite): 1024 threads/block, 3 radix rounds
// (11+11+10 bits) over a 2048-bin LDS histogram. Thread t owns tokens
// [4t, 4t+4) (one float4). Same selection semantics as the validated
// round-2 kernel: descending suffix-scan crossing bin, then stable
// (smaller-index-first) tie-break == argsort(argsort) rank.
__global__ __launch_bounds__(1024) void topk_mask_kernel(
    const float* __restrict__ keep_ratio, const float* __restrict__ scores_all,
    float* __restrict__ mask) {
  const int b = blockIdx.x;
  const float* scores = scores_all + (size_t)b * T_TOKENS;
  __shared__ int s_hist[2048];  // 8 KiB
  __shared__ int s_wtot[16];
  __shared__ unsigned int s_sel;
  __shared__ int s_krem;
  const int tid = threadIdx.x;
  const int lane = tid & 63;
  const int wv = tid >> 6;  // 16 waves

  // k = max(1, trunc(clip(kr, 0.1, 1.0) * T)); *4096 is a pure exponent
  // shift in fp32 -> exact, truncation matches jnp int32 cast bit-for-bit.
  float kf = fminf(fmaxf(keep_ratio[b], 0.1f), 1.0f);
  int k = (int)(kf * (float)T_TOKENS);
  if (k < 1) k = 1;

  // 4 contiguous scores -> order-preserving uint keys.
  unsigned int key[4];
  {
    float4 s4 = *reinterpret_cast<const float4*>(scores + tid * 4);
    float ss[4] = {s4.x, s4.y, s4.z, s4.w};
#pragma unroll
    for (int j = 0; j < 4; ++j) {
      unsigned int u = __float_as_uint(ss[j]);
      key[j] = (u & 0x80000000u) ? ~u : (u | 0x80000000u);
    }
  }

  // 3-round radix descent: shifts {21,10,0}, widths {11,11,10}.
  const int shifts[3] = {21, 10, 0};
  const int nbins_arr[3] = {2048, 2048, 1024};
  unsigned int prefix = 0u;
  int krem = k;
#pragma unroll
  for (int round = 0; round < 3; ++round) {
    const int shift = shifts[round];
    const int nbins = nbins_arr[round];
    const unsigned int bmask = (unsigned int)(nbins - 1);
    const unsigned int pmask =
        (round == 0) ? 0u : ~((1u << shifts[round - 1]) - 1u);

    s_hist[tid] = 0;
    s_hist[tid + 1024] = 0;
    __syncthreads();
#pragma unroll
    for (int j = 0; j < 4; ++j) {
      if ((key[j] & pmask) == prefix)
        atomicAdd(&s_hist[(key[j] >> shift) & bmask], 1);
    }
    __syncthreads();

    // Descending suffix scan. Thread t owns bins {2t, 2t+1}; wave w covers
    // bins [128w, 128w+128). x = sum of pair-counts for lanes >= lane.
    const int h0 = s_hist[2 * tid];
    const int h1 = s_hist[2 * tid + 1];
    int x = h0 + h1;
#pragma unroll
    for (int off = 1; off < 64; off <<= 1) {
      int y = __shfl_down(x, off);
      if (lane + off < 64) x += y;
    }
    if (lane == 0) s_wtot[wv] = x;
    __syncthreads();
    int add = 0;
    for (int w = wv + 1; w < 16; ++w) add += s_wtot[w];
    // bin 2t:   incl0 = x + add,        excl0 = incl0 - h0
    // bin 2t+1: incl1 = x + add - h0,   excl1 = incl1 - h1
    const int incl0 = x + add;
    const int incl1 = incl0 - h0;
    const int excl0 = incl1;
    const int excl1 = incl1 - h1;
    if (h0 > 0 && excl0 < krem && incl0 >= krem && 2 * tid < nbins) {
      s_sel = (unsigned int)(2 * tid);
      s_krem = krem - excl0;
    }
    if (h1 > 0 && excl1 < krem && incl1 >= krem && 2 * tid + 1 < nbins) {
      s_sel = (unsigned int)(2 * tid + 1);
      s_krem = krem - excl1;
    }
    __syncthreads();
    prefix |= (s_sel << shift);
    krem = s_krem;
    __syncthreads();
  }
  // prefix = key of k-th largest; krem = # ties (by index order) to keep.

  // Stable tie-break: exclusive count of equal keys at smaller token index
  // (tokens ascend with tid: thread t owns 4t..4t+3).
  int cnt = 0;
#pragma unroll
  for (int j = 0; j < 4; ++j) cnt += (key[j] == prefix) ? 1 : 0;
  int inc = cnt;
#pragma unroll
  for (int off = 1; off < 64; off <<= 1) {
    int y = __shfl_up(inc, off);
    if (lane >= off) inc += y;
  }
  if (lane == 63) s_wtot[wv] = inc;
  __syncthreads();
  int waveoff = 0;
  for (int w = 0; w < wv; ++w) waveoff += s_wtot[w];
  int run = waveoff + inc - cnt;  // equal keys strictly before my first token

  float4 m4;
  float mv[4];
#pragma unroll
  for (int j = 0; j < 4; ++j) {
    unsigned int kk = key[j];
    bool keep = (kk > prefix) || (kk == prefix && run < krem);
    run += (kk == prefix) ? 1 : 0;
    mv[j] = keep ? 1.0f : 0.0f;
  }
  m4.x = mv[0]; m4.y = mv[1]; m4.z = mv[2]; m4.w = mv[3];
  *reinterpret_cast<float4*>(mask + (size_t)b * T_TOKENS + tid * 4) = m4;
}

extern "C" void kernel_launch(void* const* d_in, const int* in_sizes, int n_in,
                              void* d_out, int out_size, void* d_ws, size_t ws_size,
                              hipStream_t stream) {
  const float* hidden = (const float*)d_in[0];
  const float* keep_ratio = (const float*)d_in[1];
  const float* W = (const float*)d_in[2];
  const float* bptr = (const float*)d_in[3];

  const int B = in_sizes[1];
  const int n_tokens = in_sizes[0] / C_DIM;  // B*T = 32768

  float* out = (float*)d_out;
  float* mask = out;                       // output 0: [B, T] mask as 0/1 float
  float* scores = out + (size_t)n_tokens;  // output 1: [B, T] fp32 scores

  const int blocks = (n_tokens + 3) / 4;  // 4 waves/block, 1 token/wave
  score_kernel<<<blocks, 256, 0, stream>>>(hidden, W, bptr, scores, n_tokens);
  topk_mask_kernel<<<B, 1024, 0, stream>>>(keep_ratio, scores, mask);
}